// Round 5
// baseline (186.855 us; speedup 1.0000x reference)
//
#include <hip/hip_runtime.h>

namespace {
constexpr float GRAVITY     = 10.0f;
constexpr float MAIN_THRUST = 6.0f;
constexpr float DT          = 0.02f;
constexpr int   BLK         = 256;
constexpr int   CHUNK       = 256;  // elements per chunk (== BLK)
constexpr int   ROWPAD      = 44;   // 36->44 words: 16B-aligned rows; 44%32=12
                                    // -> ds_*_b128 row access conflict-free
}

// Native vector types: __builtin_nontemporal_* requires these, not HIP_vector_type.
typedef float nfloat4 __attribute__((ext_vector_type(4)));
typedef float nfloat2 __attribute__((ext_vector_type(2)));

// Q (6x6) and R (3x3 packed: R00,R10,R11,R20,R21,R22) are batch-uniform.
__global__ void qr_precompute(const float* __restrict__ qld,
                              const float* __restrict__ qod,
                              const float* __restrict__ rld,
                              const float* __restrict__ rod,
                              float* __restrict__ out)   // 42 floats
{
    if (threadIdx.x != 0 || blockIdx.x != 0) return;
    float L[6][6];
    for (int i = 0; i < 6; ++i)
        for (int j = 0; j < 6; ++j) L[i][j] = 0.0f;
    for (int i = 0; i < 6; ++i) L[i][i] = expf(qld[i]);
    L[1][0] = qod[0];
    L[2][0] = qod[1];  L[2][1] = qod[2];
    L[3][0] = qod[3];  L[3][1] = qod[4];  L[3][2] = qod[5];
    L[4][0] = qod[6];  L[4][1] = qod[7];  L[4][2] = qod[8];  L[4][3] = qod[9];
    L[5][0] = qod[10]; L[5][1] = qod[11]; L[5][2] = qod[12]; L[5][3] = qod[13];
    L[5][4] = qod[14];
    for (int i = 0; i < 6; ++i)
        for (int j = 0; j < 6; ++j) {
            float s = 0.0f;
            const int m = i < j ? i : j;
            for (int k = 0; k <= m; ++k) s += L[i][k] * L[j][k];
            if (i == j) s += 1e-6f;
            out[i * 6 + j] = s;
        }
    const float rd0 = expf(rld[0]), rd1 = expf(rld[1]), rd2 = expf(rld[2]);
    const float ro0 = rod[0], ro1 = rod[1], ro2 = rod[2];
    out[36] = rd0 * rd0 + 1e-6f;
    out[37] = ro0 * rd0;
    out[38] = ro0 * ro0 + rd1 * rd1 + 1e-6f;
    out[39] = ro1 * rd0;
    out[40] = ro1 * ro0 + ro2 * rd1;
    out[41] = ro1 * ro1 + ro2 * ro2 + rd2 * rd2 + 1e-6f;
}

// Coalesced chunk load into registers (9 nfloat4 / thread), nontemporal.
__device__ __forceinline__ void load_chunk(const nfloat4* __restrict__ gP4,
                                           int t, int count4, nfloat4 pf[9]) {
    #pragma unroll
    for (int k = 0; k < 9; ++k) {
        const int g4 = t + k * BLK;
        if (g4 < count4) pf[k] = __builtin_nontemporal_load(&gP4[g4]);
    }
}

// Registers -> LDS scatter (padded rows).
__device__ __forceinline__ void stage_in(const nfloat4 pf[9], float* smem,
                                         int t, int count4) {
    #pragma unroll
    for (int k = 0; k < 9; ++k) {
        const int g4 = t + k * BLK;
        if (g4 < count4) {
            const int elem = g4 / 9;
            const int off4 = g4 % 9;
            *reinterpret_cast<nfloat4*>(&smem[elem * ROWPAD + off4 * 4]) = pf[k];
        }
    }
}

// LDS gather -> coalesced nontemporal global store.
__device__ __forceinline__ void stage_out(nfloat4* __restrict__ oP4,
                                          const float* smem, int t, int count4) {
    #pragma unroll
    for (int k = 0; k < 9; ++k) {
        const int g4 = t + k * BLK;
        if (g4 < count4) {
            const int elem = g4 / 9;
            const int off4 = g4 % 9;
            const nfloat4 v = *reinterpret_cast<const nfloat4*>(&smem[elem * ROWPAD + off4 * 4]);
            __builtin_nontemporal_store(v, &oP4[g4]);
        }
    }
}

// Two chunks per block, register-prefetch pipelined:
//   load(c0) -> stageIn(c0) -> load(c1) issued -> compute(c0) -> store(c0)
//            -> stageIn(c1) [c1 arrived during compute] -> compute(c1) -> store(c1)
// Update uses the exact identity  IKH*P*IKH^T + K*R*K^T == P_pred - K*(H P_pred).
__global__ __launch_bounds__(BLK, 3) void ekf_kernel(
    const float* __restrict__ z,        // (B,3)
    const float* __restrict__ u,        // (B,2)
    const float* __restrict__ x_prev,   // (B,6)
    const float* __restrict__ P_prev,   // (B,36)
    const float* __restrict__ qr,       // (42,) uniform
    float* __restrict__ x_out,          // (B,6)
    float* __restrict__ P_out,          // (B,36)
    int B)
{
    __shared__ float smem[BLK * ROWPAD];   // 45056 B -> 3 blocks/CU

    const int t  = threadIdx.x;
    const int c0 = blockIdx.x;
    const int c1 = blockIdx.x + gridDim.x;
    const int nchunk = (B + CHUNK - 1) / CHUNK;

    const int base0   = c0 * CHUNK;
    const int nE0     = min(B - base0, CHUNK);
    const int count40 = nE0 * 9;
    const bool has1   = (c1 < nchunk);
    const int base1   = has1 ? c1 * CHUNK : 0;
    const int nE1     = has1 ? min(B - base1, CHUNK) : 0;
    const int count41 = nE1 * 9;

    auto do_compute = [&](int base, int nE) {
        if (t >= nE) return;
        const int b = base + t;

        const float R00 = qr[36], R10 = qr[37], R11 = qr[38];
        const float R20 = qr[39], R21 = qr[40], R22 = qr[41];

        const nfloat2* xp2 = reinterpret_cast<const nfloat2*>(x_prev + 6 * b);
        const nfloat2 x01 = xp2[0], x23 = xp2[1], x45 = xp2[2];
        const float px = x01.x, py = x01.y, vx = x23.x, vy = x23.y;
        const float th = x45.x, om = x45.y;

        const nfloat2 uu = *reinterpret_cast<const nfloat2*>(u + 2 * b);
        const float mp  = fminf(fmaxf(uu.x, 0.0f), 1.0f);
        const float lat = uu.y;

        float s_th, c_th;
        __sincosf(th, &s_th, &c_th);

        const float Tm  = MAIN_THRUST * mp;
        const float ax  = -Tm * s_th;
        const float ay  =  Tm * c_th - GRAVITY;
        const float nvx = vx + ax * DT;
        const float nvy = vy + ay * DT;
        const float nom = om + lat * DT;          // SIDE_TORQUE = 1
        const float npx = px + nvx * DT;
        const float npy = py + nvy * DT;
        const float nth = th + nom * DT;
        const float xp[6] = {npx, npy, nvx, nvy, nth, nom};

        const float f24 = -Tm * c_th * DT;
        const float f34 = -Tm * s_th * DT;
        const float f04 = f24 * DT;
        const float f14 = f34 * DT;

        float P[36];
        const float* myrow = &smem[t * ROWPAD];
        #pragma unroll
        for (int k = 0; k < 9; ++k) {
            const nfloat4 v = *reinterpret_cast<const nfloat4*>(&myrow[k * 4]);
            P[4 * k + 0] = v.x; P[4 * k + 1] = v.y;
            P[4 * k + 2] = v.z; P[4 * k + 3] = v.w;
        }

        // P_pred = F P F^T + Q, in place
        #pragma unroll
        for (int j = 0; j < 6; ++j) {
            P[0 * 6 + j] += DT * P[2 * 6 + j] + f04 * P[4 * 6 + j];
            P[1 * 6 + j] += DT * P[3 * 6 + j] + f14 * P[4 * 6 + j];
            P[2 * 6 + j] += f24 * P[4 * 6 + j];
            P[3 * 6 + j] += f34 * P[4 * 6 + j];
            P[4 * 6 + j] += DT * P[5 * 6 + j];
        }
        #pragma unroll
        for (int i = 0; i < 6; ++i) {
            const float m0 = P[i * 6 + 0], m1 = P[i * 6 + 1], m2 = P[i * 6 + 2];
            const float m3 = P[i * 6 + 3], m4 = P[i * 6 + 4], m5 = P[i * 6 + 5];
            P[i * 6 + 0] = m0 + DT * m2 + f04 * m4 + qr[i * 6 + 0];
            P[i * 6 + 1] = m1 + DT * m3 + f14 * m4 + qr[i * 6 + 1];
            P[i * 6 + 2] = m2 + f24 * m4 + qr[i * 6 + 2];
            P[i * 6 + 3] = m3 + f34 * m4 + qr[i * 6 + 3];
            P[i * 6 + 4] = m4 + DT * m5 + qr[i * 6 + 4];
            P[i * 6 + 5] = m5 + qr[i * 6 + 5];
        }

        const float* zp = z + 3 * b;
        const float y0 = zp[0] - npx;
        const float y1 = zp[1] - npy;
        const float y2 = zp[2] - nth;

        const float s00 = P[0 * 6 + 0] + R00;
        const float s01 = P[0 * 6 + 1] + R10;
        const float s02 = P[0 * 6 + 4] + R20;
        const float s10 = P[1 * 6 + 0] + R10;
        const float s11 = P[1 * 6 + 1] + R11;
        const float s12 = P[1 * 6 + 4] + R21;
        const float s20 = P[4 * 6 + 0] + R20;
        const float s21 = P[4 * 6 + 1] + R21;
        const float s22 = P[4 * 6 + 4] + R22;

        const float det = s00 * (s11 * s22 - s12 * s21)
                        + s01 * (s12 * s20 - s10 * s22)
                        + s02 * (s10 * s21 - s11 * s20);
        const float invd = 1.0f / det;
        const float i00 = (s11 * s22 - s12 * s21) * invd;
        const float i01 = (s02 * s21 - s01 * s22) * invd;
        const float i02 = (s01 * s12 - s02 * s11) * invd;
        const float i10 = (s12 * s20 - s10 * s22) * invd;
        const float i11 = (s00 * s22 - s02 * s20) * invd;
        const float i12 = (s02 * s10 - s00 * s12) * invd;
        const float i20 = (s10 * s21 - s11 * s20) * invd;
        const float i21 = (s01 * s20 - s00 * s21) * invd;
        const float i22 = (s00 * s11 - s01 * s10) * invd;

        float r0[6], r1[6], r4[6];
        #pragma unroll
        for (int j = 0; j < 6; ++j) {
            r0[j] = P[0 * 6 + j];
            r1[j] = P[1 * 6 + j];
            r4[j] = P[4 * 6 + j];
        }

        float K[6][3];
        #pragma unroll
        for (int i = 0; i < 6; ++i) {
            const float hp0 = r0[i], hp1 = r1[i], hp2 = r4[i];
            K[i][0] = i00 * hp0 + i01 * hp1 + i02 * hp2;
            K[i][1] = i10 * hp0 + i11 * hp1 + i12 * hp2;
            K[i][2] = i20 * hp0 + i21 * hp1 + i22 * hp2;
        }

        nfloat2* xo2 = reinterpret_cast<nfloat2*>(x_out + 6 * b);
        float xu[6];
        #pragma unroll
        for (int i = 0; i < 6; ++i)
            xu[i] = xp[i] + K[i][0] * y0 + K[i][1] * y1 + K[i][2] * y2;
        nfloat2 o01; o01.x = xu[0]; o01.y = xu[1];
        nfloat2 o23; o23.x = xu[2]; o23.y = xu[3];
        nfloat2 o45; o45.x = xu[4]; o45.y = xu[5];
        __builtin_nontemporal_store(o01, &xo2[0]);
        __builtin_nontemporal_store(o23, &xo2[1]);
        __builtin_nontemporal_store(o45, &xo2[2]);

        // P_upd = P_pred - K * HP (exact Joseph equivalent)
        #pragma unroll
        for (int i = 0; i < 6; ++i)
            #pragma unroll
            for (int j = 0; j < 6; ++j)
                P[i * 6 + j] -= K[i][0] * r0[j] + K[i][1] * r1[j] + K[i][2] * r4[j];

        float* myrowW = &smem[t * ROWPAD];
        #pragma unroll
        for (int k = 0; k < 9; ++k) {
            nfloat4 v;
            v.x = P[4 * k + 0]; v.y = P[4 * k + 1];
            v.z = P[4 * k + 2]; v.w = P[4 * k + 3];
            *reinterpret_cast<nfloat4*>(&myrowW[k * 4]) = v;
        }
    };

    // ---------------- pipeline ----------------
    nfloat4 pfA[9];
    load_chunk(reinterpret_cast<const nfloat4*>(P_prev + (size_t)base0 * 36),
               t, count40, pfA);

    // chunk 0
    stage_in(pfA, smem, t, count40);            // waits on pfA arrival
    nfloat4 pfB[9];
    if (has1)
        load_chunk(reinterpret_cast<const nfloat4*>(P_prev + (size_t)base1 * 36),
                   t, count41, pfB);            // in flight across compute(c0)
    __syncthreads();
    do_compute(base0, nE0);
    __syncthreads();
    stage_out(reinterpret_cast<nfloat4*>(P_out + (size_t)base0 * 36),
              smem, t, count40);

    if (has1) {
        __syncthreads();                        // LDS reads of c0 done
        stage_in(pfB, smem, t, count41);        // pfB arrived long ago
        __syncthreads();
        do_compute(base1, nE1);
        __syncthreads();
        stage_out(reinterpret_cast<nfloat4*>(P_out + (size_t)base1 * 36),
                  smem, t, count41);
    }
}

extern "C" void kernel_launch(void* const* d_in, const int* in_sizes, int n_in,
                              void* d_out, int out_size, void* d_ws, size_t ws_size,
                              hipStream_t stream) {
    const float* z          = (const float*)d_in[0];
    const float* u          = (const float*)d_in[1];
    const float* x_prev     = (const float*)d_in[2];
    const float* P_prev     = (const float*)d_in[3];
    const float* q_log_diag = (const float*)d_in[4];
    const float* q_off_diag = (const float*)d_in[5];
    const float* r_log_diag = (const float*)d_in[6];
    const float* r_off_diag = (const float*)d_in[7];

    const int B = in_sizes[0] / 3;                 // z is (B,3)
    float* x_out = (float*)d_out;                  // (B,6)
    float* P_out = (float*)d_out + (size_t)B * 6;  // (B,36)
    float* qrbuf = (float*)d_ws;                   // 42 floats

    qr_precompute<<<1, 64, 0, stream>>>(q_log_diag, q_off_diag,
                                        r_log_diag, r_off_diag, qrbuf);

    const int nchunk = (B + CHUNK - 1) / CHUNK;    // 2048 at B=524288
    const int grid   = (nchunk + 1) / 2;           // two chunks per block
    ekf_kernel<<<grid, BLK, 0, stream>>>(z, u, x_prev, P_prev, qrbuf,
                                         x_out, P_out, B);
}

// Round 6
// 186.026 us; speedup vs baseline: 1.0045x; 1.0045x over previous
//
#include <hip/hip_runtime.h>

namespace {
constexpr float GRAVITY     = 10.0f;
constexpr float MAIN_THRUST = 6.0f;
constexpr float DT          = 0.02f;
constexpr int   BLK         = 256;
constexpr int   CHUNK       = 256;  // elements per chunk (== BLK)
constexpr int   ROWPAD      = 44;   // 36->44 words: 16B-aligned rows; 44%32=12
                                    // -> ds_*_b128 row access conflict-free
constexpr int   GRID        = 512;  // 4 chunks/block at B=524288: 1 cold load,
                                    // 3 prefetch-hidden
}

// Native vector types: __builtin_nontemporal_* requires these, not HIP_vector_type.
typedef float nfloat4 __attribute__((ext_vector_type(4)));
typedef float nfloat2 __attribute__((ext_vector_type(2)));

// Q (6x6) and R (3x3 packed: R00,R10,R11,R20,R21,R22) are batch-uniform.
__global__ void qr_precompute(const float* __restrict__ qld,
                              const float* __restrict__ qod,
                              const float* __restrict__ rld,
                              const float* __restrict__ rod,
                              float* __restrict__ out)   // 42 floats
{
    if (threadIdx.x != 0 || blockIdx.x != 0) return;
    float L[6][6];
    for (int i = 0; i < 6; ++i)
        for (int j = 0; j < 6; ++j) L[i][j] = 0.0f;
    for (int i = 0; i < 6; ++i) L[i][i] = expf(qld[i]);
    L[1][0] = qod[0];
    L[2][0] = qod[1];  L[2][1] = qod[2];
    L[3][0] = qod[3];  L[3][1] = qod[4];  L[3][2] = qod[5];
    L[4][0] = qod[6];  L[4][1] = qod[7];  L[4][2] = qod[8];  L[4][3] = qod[9];
    L[5][0] = qod[10]; L[5][1] = qod[11]; L[5][2] = qod[12]; L[5][3] = qod[13];
    L[5][4] = qod[14];
    for (int i = 0; i < 6; ++i)
        for (int j = 0; j < 6; ++j) {
            float s = 0.0f;
            const int m = i < j ? i : j;
            for (int k = 0; k <= m; ++k) s += L[i][k] * L[j][k];
            if (i == j) s += 1e-6f;
            out[i * 6 + j] = s;
        }
    const float rd0 = expf(rld[0]), rd1 = expf(rld[1]), rd2 = expf(rld[2]);
    const float ro0 = rod[0], ro1 = rod[1], ro2 = rod[2];
    out[36] = rd0 * rd0 + 1e-6f;
    out[37] = ro0 * rd0;
    out[38] = ro0 * ro0 + rd1 * rd1 + 1e-6f;
    out[39] = ro1 * rd0;
    out[40] = ro1 * ro0 + ro2 * rd1;
    out[41] = ro1 * ro1 + ro2 * ro2 + rd2 * rd2 + 1e-6f;
}

// Coalesced chunk load into registers (9 float4 / thread). CACHED (not nt):
// inputs are L3-resident after the harness restore; nt-loads forfeit ~50 MB
// of L3 hits (R5 lesson).
__device__ __forceinline__ void load_chunk(const nfloat4* __restrict__ gP4,
                                           int t, int count4, nfloat4 pf[9]) {
    #pragma unroll
    for (int k = 0; k < 9; ++k) {
        const int g4 = t + k * BLK;
        if (g4 < count4) pf[k] = gP4[g4];
    }
}

// Registers -> LDS scatter (padded rows).
__device__ __forceinline__ void stage_in(const nfloat4 pf[9], float* smem,
                                         int t, int count4) {
    #pragma unroll
    for (int k = 0; k < 9; ++k) {
        const int g4 = t + k * BLK;
        if (g4 < count4) {
            const int elem = g4 / 9;
            const int off4 = g4 % 9;
            *reinterpret_cast<nfloat4*>(&smem[elem * ROWPAD + off4 * 4]) = pf[k];
        }
    }
}

// LDS gather -> coalesced nontemporal global store (write-once stream).
__device__ __forceinline__ void stage_out(nfloat4* __restrict__ oP4,
                                          const float* smem, int t, int count4) {
    #pragma unroll
    for (int k = 0; k < 9; ++k) {
        const int g4 = t + k * BLK;
        if (g4 < count4) {
            const int elem = g4 / 9;
            const int off4 = g4 % 9;
            const nfloat4 v = *reinterpret_cast<const nfloat4*>(&smem[elem * ROWPAD + off4 * 4]);
            __builtin_nontemporal_store(v, &oP4[g4]);
        }
    }
}

// Grid-strided chunk loop, register-prefetch pipelined: while chunk c is
// computed+stored, chunk c+stride's loads are in flight. Only the first chunk
// per block pays exposed HBM latency. Update uses the exact identity
//   IKH*P*IKH^T + K*R*K^T == P_pred - K*(H P_pred)   (since K*S = HP^T).
__global__ __launch_bounds__(BLK, 3) void ekf_kernel(
    const float* __restrict__ z,        // (B,3)
    const float* __restrict__ u,        // (B,2)
    const float* __restrict__ x_prev,   // (B,6)
    const float* __restrict__ P_prev,   // (B,36)
    const float* __restrict__ qr,       // (42,) uniform
    float* __restrict__ x_out,          // (B,6)
    float* __restrict__ P_out,          // (B,36)
    int B)
{
    __shared__ float smem[BLK * ROWPAD];   // 45056 B -> 3 blocks/CU

    const int t      = threadIdx.x;
    const int nchunk = (B + CHUNK - 1) / CHUNK;
    const int stride = gridDim.x;

    auto do_compute = [&](int base, int nE) {
        if (t >= nE) return;
        const int b = base + t;

        const float R00 = qr[36], R10 = qr[37], R11 = qr[38];
        const float R20 = qr[39], R21 = qr[40], R22 = qr[41];

        const nfloat2* xp2 = reinterpret_cast<const nfloat2*>(x_prev + 6 * b);
        const nfloat2 x01 = xp2[0], x23 = xp2[1], x45 = xp2[2];
        const float px = x01.x, py = x01.y, vx = x23.x, vy = x23.y;
        const float th = x45.x, om = x45.y;

        const nfloat2 uu = *reinterpret_cast<const nfloat2*>(u + 2 * b);
        const float mp  = fminf(fmaxf(uu.x, 0.0f), 1.0f);
        const float lat = uu.y;

        float s_th, c_th;
        __sincosf(th, &s_th, &c_th);

        const float Tm  = MAIN_THRUST * mp;
        const float ax  = -Tm * s_th;
        const float ay  =  Tm * c_th - GRAVITY;
        const float nvx = vx + ax * DT;
        const float nvy = vy + ay * DT;
        const float nom = om + lat * DT;          // SIDE_TORQUE = 1
        const float npx = px + nvx * DT;
        const float npy = py + nvy * DT;
        const float nth = th + nom * DT;
        const float xp[6] = {npx, npy, nvx, nvy, nth, nom};

        const float f24 = -Tm * c_th * DT;
        const float f34 = -Tm * s_th * DT;
        const float f04 = f24 * DT;
        const float f14 = f34 * DT;

        float P[36];
        const float* myrow = &smem[t * ROWPAD];
        #pragma unroll
        for (int k = 0; k < 9; ++k) {
            const nfloat4 v = *reinterpret_cast<const nfloat4*>(&myrow[k * 4]);
            P[4 * k + 0] = v.x; P[4 * k + 1] = v.y;
            P[4 * k + 2] = v.z; P[4 * k + 3] = v.w;
        }

        // P_pred = F P F^T + Q, in place
        #pragma unroll
        for (int j = 0; j < 6; ++j) {
            P[0 * 6 + j] += DT * P[2 * 6 + j] + f04 * P[4 * 6 + j];
            P[1 * 6 + j] += DT * P[3 * 6 + j] + f14 * P[4 * 6 + j];
            P[2 * 6 + j] += f24 * P[4 * 6 + j];
            P[3 * 6 + j] += f34 * P[4 * 6 + j];
            P[4 * 6 + j] += DT * P[5 * 6 + j];
        }
        #pragma unroll
        for (int i = 0; i < 6; ++i) {
            const float m0 = P[i * 6 + 0], m1 = P[i * 6 + 1], m2 = P[i * 6 + 2];
            const float m3 = P[i * 6 + 3], m4 = P[i * 6 + 4], m5 = P[i * 6 + 5];
            P[i * 6 + 0] = m0 + DT * m2 + f04 * m4 + qr[i * 6 + 0];
            P[i * 6 + 1] = m1 + DT * m3 + f14 * m4 + qr[i * 6 + 1];
            P[i * 6 + 2] = m2 + f24 * m4 + qr[i * 6 + 2];
            P[i * 6 + 3] = m3 + f34 * m4 + qr[i * 6 + 3];
            P[i * 6 + 4] = m4 + DT * m5 + qr[i * 6 + 4];
            P[i * 6 + 5] = m5 + qr[i * 6 + 5];
        }

        const float* zp = z + 3 * b;
        const float y0 = zp[0] - npx;
        const float y1 = zp[1] - npy;
        const float y2 = zp[2] - nth;

        const float s00 = P[0 * 6 + 0] + R00;
        const float s01 = P[0 * 6 + 1] + R10;
        const float s02 = P[0 * 6 + 4] + R20;
        const float s10 = P[1 * 6 + 0] + R10;
        const float s11 = P[1 * 6 + 1] + R11;
        const float s12 = P[1 * 6 + 4] + R21;
        const float s20 = P[4 * 6 + 0] + R20;
        const float s21 = P[4 * 6 + 1] + R21;
        const float s22 = P[4 * 6 + 4] + R22;

        const float det = s00 * (s11 * s22 - s12 * s21)
                        + s01 * (s12 * s20 - s10 * s22)
                        + s02 * (s10 * s21 - s11 * s20);
        const float invd = 1.0f / det;
        const float i00 = (s11 * s22 - s12 * s21) * invd;
        const float i01 = (s02 * s21 - s01 * s22) * invd;
        const float i02 = (s01 * s12 - s02 * s11) * invd;
        const float i10 = (s12 * s20 - s10 * s22) * invd;
        const float i11 = (s00 * s22 - s02 * s20) * invd;
        const float i12 = (s02 * s10 - s00 * s12) * invd;
        const float i20 = (s10 * s21 - s11 * s20) * invd;
        const float i21 = (s01 * s20 - s00 * s21) * invd;
        const float i22 = (s00 * s11 - s01 * s10) * invd;

        float r0[6], r1[6], r4[6];
        #pragma unroll
        for (int j = 0; j < 6; ++j) {
            r0[j] = P[0 * 6 + j];
            r1[j] = P[1 * 6 + j];
            r4[j] = P[4 * 6 + j];
        }

        float K[6][3];
        #pragma unroll
        for (int i = 0; i < 6; ++i) {
            const float hp0 = r0[i], hp1 = r1[i], hp2 = r4[i];
            K[i][0] = i00 * hp0 + i01 * hp1 + i02 * hp2;
            K[i][1] = i10 * hp0 + i11 * hp1 + i12 * hp2;
            K[i][2] = i20 * hp0 + i21 * hp1 + i22 * hp2;
        }

        nfloat2* xo2 = reinterpret_cast<nfloat2*>(x_out + 6 * b);
        float xu[6];
        #pragma unroll
        for (int i = 0; i < 6; ++i)
            xu[i] = xp[i] + K[i][0] * y0 + K[i][1] * y1 + K[i][2] * y2;
        nfloat2 o01; o01.x = xu[0]; o01.y = xu[1];
        nfloat2 o23; o23.x = xu[2]; o23.y = xu[3];
        nfloat2 o45; o45.x = xu[4]; o45.y = xu[5];
        __builtin_nontemporal_store(o01, &xo2[0]);
        __builtin_nontemporal_store(o23, &xo2[1]);
        __builtin_nontemporal_store(o45, &xo2[2]);

        // P_upd = P_pred - K * HP (exact Joseph equivalent)
        #pragma unroll
        for (int i = 0; i < 6; ++i)
            #pragma unroll
            for (int j = 0; j < 6; ++j)
                P[i * 6 + j] -= K[i][0] * r0[j] + K[i][1] * r1[j] + K[i][2] * r4[j];

        float* myrowW = &smem[t * ROWPAD];
        #pragma unroll
        for (int k = 0; k < 9; ++k) {
            nfloat4 v;
            v.x = P[4 * k + 0]; v.y = P[4 * k + 1];
            v.z = P[4 * k + 2]; v.w = P[4 * k + 3];
            *reinterpret_cast<nfloat4*>(&myrowW[k * 4]) = v;
        }
    };

    // ---------------- grid-strided pipelined chunk loop ----------------
    int c = blockIdx.x;
    if (c >= nchunk) return;

    int base   = c * CHUNK;
    int nE     = min(B - base, CHUNK);
    int count4 = nE * 9;

    nfloat4 pfA[9];
    load_chunk(reinterpret_cast<const nfloat4*>(P_prev + (size_t)base * 36),
               t, count4, pfA);

    for (;;) {
        stage_in(pfA, smem, t, count4);              // waits on pfA arrival

        const int cn      = c + stride;
        const bool hasN   = (cn < nchunk);
        int baseN = 0, nEN = 0, count4N = 0;
        nfloat4 pfB[9];
        if (hasN) {                                   // issue next loads now;
            baseN   = cn * CHUNK;                     // in flight across
            nEN     = min(B - baseN, CHUNK);          // compute + store
            count4N = nEN * 9;
            load_chunk(reinterpret_cast<const nfloat4*>(P_prev + (size_t)baseN * 36),
                       t, count4N, pfB);
        }

        __syncthreads();                              // stage_in complete
        do_compute(base, nE);
        __syncthreads();                              // LDS writeback complete
        stage_out(reinterpret_cast<nfloat4*>(P_out + (size_t)base * 36),
                  smem, t, count4);

        if (!hasN) break;
        __syncthreads();                              // LDS gathers done; reuse buf

        #pragma unroll
        for (int k = 0; k < 9; ++k) pfA[k] = pfB[k];  // rotate prefetch regs
        c = cn; base = baseN; nE = nEN; count4 = count4N;
    }
}

extern "C" void kernel_launch(void* const* d_in, const int* in_sizes, int n_in,
                              void* d_out, int out_size, void* d_ws, size_t ws_size,
                              hipStream_t stream) {
    const float* z          = (const float*)d_in[0];
    const float* u          = (const float*)d_in[1];
    const float* x_prev     = (const float*)d_in[2];
    const float* P_prev     = (const float*)d_in[3];
    const float* q_log_diag = (const float*)d_in[4];
    const float* q_off_diag = (const float*)d_in[5];
    const float* r_log_diag = (const float*)d_in[6];
    const float* r_off_diag = (const float*)d_in[7];

    const int B = in_sizes[0] / 3;                 // z is (B,3)
    float* x_out = (float*)d_out;                  // (B,6)
    float* P_out = (float*)d_out + (size_t)B * 6;  // (B,36)
    float* qrbuf = (float*)d_ws;                   // 42 floats

    qr_precompute<<<1, 64, 0, stream>>>(q_log_diag, q_off_diag,
                                        r_log_diag, r_off_diag, qrbuf);

    const int nchunk = (B + CHUNK - 1) / CHUNK;    // 2048 at B=524288
    const int grid   = nchunk < GRID ? nchunk : GRID;
    ekf_kernel<<<grid, BLK, 0, stream>>>(z, u, x_prev, P_prev, qrbuf,
                                         x_out, P_out, B);
}